// Round 3
// baseline (8063.387 us; speedup 1.0000x reference)
//
#include <hip/hip_runtime.h>
#include <hip/hip_bf16.h>

#define NSTEP 50
#define BSZ   1024
#define HD    256
#define RPB   4
#define DEC_THREADS 256
#define NEG_INF (-__builtin_inff())

#define OFF_SEL ((size_t)BSZ * NSTEP * NSTEP)          // 2,560,000
#define OFF_ETA (OFF_SEL + (size_t)BSZ * NSTEP)        // 2,611,200

__device__ __forceinline__ float sigf(float x)      { return 1.f / (1.f + __expf(-x)); }
__device__ __forceinline__ float tanh_fast(float x) { return 1.f - 2.f / (__expf(2.f * x) + 1.f); }

__device__ __forceinline__ float wave_sum(float v) {
#pragma unroll
  for (int o = 1; o < 64; o <<= 1) v += __shfl_xor(v, o);
  return v;
}
__device__ __forceinline__ float wave_max(float v) {
#pragma unroll
  for (int o = 1; o < 64; o <<= 1) v = fmaxf(v, __shfl_xor(v, o));
  return v;
}

// wT2[k][4*col+g] = W[g*256+col][k], W = [w_ih | w_hh] along k; bc[j] = b_ih[j]+b_hh[j]
__global__ __launch_bounds__(256) void init_kernel(
    const float* __restrict__ w_ih, const float* __restrict__ w_hh,
    const float* __restrict__ b_ih, const float* __restrict__ b_hh,
    float* __restrict__ wT2, float* __restrict__ bc)
{
  const int bid = blockIdx.x, tid = threadIdx.x;
  if (bid < 512) {
    const int k = bid;
    const float* src = (k < 256) ? (w_ih + k) : (w_hh + (k - 256));
#pragma unroll
    for (int g = 0; g < 4; ++g)
      wT2[(size_t)k * 1024 + tid * 4 + g] = src[(size_t)(g * 256 + tid) * 256];
  } else {
    const int j = (bid - 512) * 256 + tid;
    bc[j] = b_ih[j] + b_hh[j];
  }
}

// e[b][n][g] = sum_h context[n][b][h]*wr[g][h] + br[g]
__global__ __launch_bounds__(256) void e_kernel(
    const float* __restrict__ context,
    const float* __restrict__ glp_wr, const float* __restrict__ glp_br,
    const float* __restrict__ ptr_wr, const float* __restrict__ ptr_br,
    float* __restrict__ e_glp, float* __restrict__ e_ptr)
{
  __shared__ float ctx_lds[32][256];
  const int tid = threadIdx.x;
  const int n   = blockIdx.x >> 5;
  const int b0  = (blockIdx.x & 31) << 5;
  const float* src = context + ((size_t)n * BSZ + b0) * HD;
  for (int i = tid; i < 32 * 64; i += 256) {
    const int row = i >> 6, k4 = (i & 63) << 2;
    *(float4*)&ctx_lds[row][k4] = *(const float4*)&src[row * HD + k4];
  }
  __syncthreads();
  const int g  = tid;
  const float bg = glp_br[g], bp = ptr_br[g];
  for (int rg = 0; rg < 2; ++rg) {
    float ag[16], ap[16];
#pragma unroll
    for (int i = 0; i < 16; ++i) { ag[i] = 0.f; ap[i] = 0.f; }
    for (int k = 0; k < 256; k += 4) {
      float4 wg = *(const float4*)&glp_wr[g * HD + k];
      float4 wp = *(const float4*)&ptr_wr[g * HD + k];
#pragma unroll
      for (int i = 0; i < 16; ++i) {
        float4 a = *(const float4*)&ctx_lds[rg * 16 + i][k];
        ag[i] += a.x * wg.x + a.y * wg.y + a.z * wg.z + a.w * wg.w;
        ap[i] += a.x * wp.x + a.y * wp.y + a.z * wp.z + a.w * wp.w;
      }
    }
#pragma unroll
    for (int i = 0; i < 16; ++i) {
      const int b = b0 + rg * 16 + i;
      e_glp[((size_t)b * NSTEP + n) * HD + g] = ag[i] + bg;
      e_ptr[((size_t)b * NSTEP + n) * HD + g] = ap[i] + bp;
    }
  }
}

// zx[n][b][4*col+g] = x_n[b] @ w_ih^T  (n==NSTEP slot -> decoder_input), permuted j layout
__global__ __launch_bounds__(256) void zx_kernel(
    const float* __restrict__ embedded, const float* __restrict__ decoder_input,
    const float* __restrict__ wT2, float* __restrict__ zx)
{
  __shared__ float x_lds[32][256];
  const int tid = threadIdx.x;
  const int n   = blockIdx.x >> 5;
  const int b0  = (blockIdx.x & 31) << 5;
  const float* src = (n < NSTEP) ? (embedded + ((size_t)n * BSZ + b0) * HD)
                                 : (decoder_input + (size_t)b0 * HD);
  for (int i = tid; i < 32 * 64; i += 256) {
    const int row = i >> 6, k4 = (i & 63) << 2;
    *(float4*)&x_lds[row][k4] = *(const float4*)&src[row * HD + k4];
  }
  __syncthreads();
  const float* wp = wT2 + (tid << 2);
  for (int rg = 0; rg < 2; ++rg) {
    float4 acc[16];
#pragma unroll
    for (int i = 0; i < 16; ++i) acc[i] = make_float4(0.f, 0.f, 0.f, 0.f);
    for (int k = 0; k < 256; k += 4) {
      float4 w0 = *(const float4*)(wp + (size_t)(k + 0) * 1024);
      float4 w1 = *(const float4*)(wp + (size_t)(k + 1) * 1024);
      float4 w2 = *(const float4*)(wp + (size_t)(k + 2) * 1024);
      float4 w3 = *(const float4*)(wp + (size_t)(k + 3) * 1024);
#pragma unroll
      for (int i = 0; i < 16; ++i) {
        float4 a = *(const float4*)&x_lds[rg * 16 + i][k];
        acc[i].x += a.x * w0.x + a.y * w1.x + a.z * w2.x + a.w * w3.x;
        acc[i].y += a.x * w0.y + a.y * w1.y + a.z * w2.y + a.w * w3.y;
        acc[i].z += a.x * w0.z + a.y * w1.z + a.z * w2.z + a.w * w3.z;
        acc[i].w += a.x * w0.w + a.y * w1.w + a.z * w2.w + a.w * w3.w;
      }
    }
#pragma unroll
    for (int i = 0; i < 16; ++i)
      *(float4*)&zx[((size_t)n * BSZ + (b0 + rg * 16 + i)) * 1024 + (tid << 2)] = acc[i];
  }
}

// persistent decoder: 256 blocks x 256 threads, 4 rows/block, 50 steps
template <int PRE>
__global__ __launch_bounds__(DEC_THREADS) void dec_kernel(
    const float* __restrict__ start_fea,
    const float* __restrict__ decoder_input,
    const float* __restrict__ embedded,
    const float* __restrict__ hidden_h,
    const float* __restrict__ hidden_c,
    const float* __restrict__ context,
    const unsigned char* __restrict__ vmask,
    const float* __restrict__ glp_wq, const float* __restrict__ glp_bq, const float* __restrict__ glp_v,
    const float* __restrict__ ptr_wq, const float* __restrict__ ptr_bq, const float* __restrict__ ptr_v,
    const float* __restrict__ fn_w,
    const float* __restrict__ eta_lw, const float* __restrict__ eta_lb,
    const float* __restrict__ wT2, const float* __restrict__ bc,
    const float* __restrict__ e_glp, const float* __restrict__ e_ptr,
    const float* __restrict__ zx,
    float* __restrict__ out)
{
  __shared__ float a_lds[RPB][512];     // PRE: h at [r][0..255]; else x|h
  __shared__ float q_lds[RPB][256];
  __shared__ float q2_lds[RPB][256];
  __shared__ float u_lds[RPB][64];
  __shared__ float p_lds[RPB][64];
  __shared__ unsigned char mask_lds[RPB][64];
  __shared__ int   idx_lds[RPB];
  __shared__ float red_lds[4][RPB];
  __shared__ float eta_lds[RPB];

  const int tid  = threadIdx.x;
  const int col  = tid;
  const int wav  = tid >> 6;
  const int lane = tid & 63;
  const int b0   = blockIdx.x * RPB;
  constexpr int HOFF = PRE ? 0 : 256;

  float c_reg[RPB], ln_reg[RPB];
  int   nsel[RPB];

#pragma unroll
  for (int i = 0; i < RPB; ++i) {
    const int b = b0 + i;
    if (!PRE) a_lds[i][col] = decoder_input[(size_t)b * HD + col];
    a_lds[i][HOFF + col] = hidden_h[(size_t)b * HD + col];
    c_reg[i] = hidden_c[(size_t)b * HD + col];
    float fn = 0.f;
#pragma unroll
    for (int k = 0; k < 5; ++k) fn += start_fea[b * 5 + k] * fn_w[col * 5 + k];
    ln_reg[i] = fn;
    nsel[i] = NSTEP;   // decoder_input slot for t=0
  }
  if (tid < RPB * NSTEP) {
    const int r = tid / NSTEP, n = tid - r * NSTEP;
    mask_lds[r][n] = vmask[(size_t)(b0 + r) * NSTEP + n];
  }
  if (tid < RPB) eta_lds[tid] = 0.f;
  __syncthreads();
  if (tid < RPB) {
    bool all = true;
    for (int n = 0; n < NSTEP; ++n) all = all && (mask_lds[tid][n] != 0);
    if (all) mask_lds[tid][NSTEP - 1] = 0;
  }
  __syncthreads();

  const float bcv0 = bc[col], bcv1 = bc[col + 256], bcv2 = bc[col + 512], bcv3 = bc[col + 768];
  const float bqg = glp_bq[col], bqp = ptr_bq[col];
  const float lw0 = eta_lw[col], lw1 = eta_lw[HD + col];
  const float etaB = eta_lb[0];
  const float4 v4g = *(const float4*)&glp_v[lane << 2];
  const float4 v4p = *(const float4*)&ptr_v[lane << 2];

  for (int t = 0; t < NSTEP; ++t) {
    // ---- A: LSTM preacts (gate-local accumulation, permuted wT2) ----
    float4 acc[RPB];
    if (PRE) {
#pragma unroll
      for (int i = 0; i < RPB; ++i)
        acc[i] = *(const float4*)&zx[((size_t)nsel[i] * BSZ + (b0 + i)) * 1024 + (col << 2)];
      const float* wp = wT2 + (size_t)256 * 1024 + (col << 2);
      for (int k = 0; k < 256; k += 4) {
        float4 w0 = *(const float4*)(wp + (size_t)(k + 0) * 1024);
        float4 w1 = *(const float4*)(wp + (size_t)(k + 1) * 1024);
        float4 w2 = *(const float4*)(wp + (size_t)(k + 2) * 1024);
        float4 w3 = *(const float4*)(wp + (size_t)(k + 3) * 1024);
#pragma unroll
        for (int i = 0; i < RPB; ++i) {
          float4 a = *(const float4*)&a_lds[i][k];
          acc[i].x += a.x * w0.x + a.y * w1.x + a.z * w2.x + a.w * w3.x;
          acc[i].y += a.x * w0.y + a.y * w1.y + a.z * w2.y + a.w * w3.y;
          acc[i].z += a.x * w0.z + a.y * w1.z + a.z * w2.z + a.w * w3.z;
          acc[i].w += a.x * w0.w + a.y * w1.w + a.z * w2.w + a.w * w3.w;
        }
      }
    } else {
#pragma unroll
      for (int i = 0; i < RPB; ++i) acc[i] = make_float4(0.f, 0.f, 0.f, 0.f);
      const float* wp = wT2 + (col << 2);
      for (int k = 0; k < 512; k += 4) {
        float4 w0 = *(const float4*)(wp + (size_t)(k + 0) * 1024);
        float4 w1 = *(const float4*)(wp + (size_t)(k + 1) * 1024);
        float4 w2 = *(const float4*)(wp + (size_t)(k + 2) * 1024);
        float4 w3 = *(const float4*)(wp + (size_t)(k + 3) * 1024);
#pragma unroll
        for (int i = 0; i < RPB; ++i) {
          float4 a = *(const float4*)&a_lds[i][k];
          acc[i].x += a.x * w0.x + a.y * w1.x + a.z * w2.x + a.w * w3.x;
          acc[i].y += a.x * w0.y + a.y * w1.y + a.z * w2.y + a.w * w3.y;
          acc[i].z += a.x * w0.z + a.y * w1.z + a.z * w2.z + a.w * w3.z;
          acc[i].w += a.x * w0.w + a.y * w1.w + a.z * w2.w + a.w * w3.w;
        }
      }
    }
    float h_reg[RPB];
#pragma unroll
    for (int i = 0; i < RPB; ++i) {
      const float zi = acc[i].x + bcv0;
      const float zf = acc[i].y + bcv1;
      const float zg = acc[i].z + bcv2;
      const float zo = acc[i].w + bcv3;
      const float cn = sigf(zf) * c_reg[i] + sigf(zi) * tanh_fast(zg);
      c_reg[i] = cn;
      h_reg[i] = sigf(zo) * tanh_fast(cn);
    }
    __syncthreads();   // everyone done reading a_lds h before overwrite
#pragma unroll
    for (int i = 0; i < RPB; ++i) a_lds[i][HOFF + col] = h_reg[i];
    __syncthreads();
    // ---- B: q_glp = h @ glp_wq^T + bq ----
    {
      float accq[RPB] = {0.f, 0.f, 0.f, 0.f};
      for (int k = 0; k < 256; k += 4) {
        float4 w = *(const float4*)&glp_wq[col * HD + k];
#pragma unroll
        for (int i = 0; i < RPB; ++i) {
          float4 h4 = *(const float4*)&a_lds[i][HOFF + k];
          accq[i] += h4.x * w.x + h4.y * w.y + h4.z * w.z + h4.w * w.w;
        }
      }
#pragma unroll
      for (int i = 0; i < RPB; ++i) q_lds[i][col] = accq[i] + bqg;
    }
    __syncthreads();
    // ---- C: u_glp[n] ----
    {
      const int r = wav, b = b0 + r;
      const float* eb = e_glp + (size_t)b * NSTEP * HD;
      const float4 q4 = *(const float4*)&q_lds[r][lane << 2];
      for (int n = 0; n < NSTEP; ++n) {
        float4 e4 = *(const float4*)&eb[n * HD + (lane << 2)];
        float s = v4g.x * tanh_fast(q4.x + e4.x) + v4g.y * tanh_fast(q4.y + e4.y)
                + v4g.z * tanh_fast(q4.z + e4.z) + v4g.w * tanh_fast(q4.w + e4.w);
        s = wave_sum(s);
        if (lane == 0) u_lds[r][n] = s;
      }
    }
    __syncthreads();
    // ---- C2: masked softmax ----
    {
      const int r = wav;
      const bool mk = (lane < NSTEP) ? (mask_lds[r][lane] != 0) : true;
      const float uv = (!mk) ? u_lds[r][lane] : NEG_INF;
      const float m  = wave_max(uv);
      const float ex = (lane < NSTEP) ? __expf(uv - m) : 0.f;
      const float ss = wave_sum(ex);
      p_lds[r][lane] = ex / ss;
    }
    __syncthreads();
    // ---- D: g_l = e_glp^T p -> q2 ----
    {
      float accd[RPB] = {0.f, 0.f, 0.f, 0.f};
      for (int n = 0; n < NSTEP; ++n) {
#pragma unroll
        for (int i = 0; i < RPB; ++i)
          accd[i] += e_glp[((size_t)(b0 + i) * NSTEP + n) * HD + col] * p_lds[i][n];
      }
#pragma unroll
      for (int i = 0; i < RPB; ++i) q2_lds[i][col] = accd[i];
    }
    __syncthreads();
    // ---- E: q_ptr = g_l @ ptr_wq^T + bq -> q_lds ----
    {
      float acce[RPB] = {0.f, 0.f, 0.f, 0.f};
      for (int k = 0; k < 256; k += 4) {
        float4 w = *(const float4*)&ptr_wq[col * HD + k];
#pragma unroll
        for (int i = 0; i < RPB; ++i) {
          float4 g4 = *(const float4*)&q2_lds[i][k];
          acce[i] += g4.x * w.x + g4.y * w.y + g4.z * w.z + g4.w * w.w;
        }
      }
#pragma unroll
      for (int i = 0; i < RPB; ++i) q_lds[i][col] = acce[i] + bqp;
    }
    __syncthreads();
    // ---- F: u_ptr ----
    {
      const int r = wav, b = b0 + r;
      const float* eb = e_ptr + (size_t)b * NSTEP * HD;
      const float4 q4 = *(const float4*)&q_lds[r][lane << 2];
      for (int n = 0; n < NSTEP; ++n) {
        float4 e4 = *(const float4*)&eb[n * HD + (lane << 2)];
        float s = v4p.x * tanh_fast(q4.x + e4.x) + v4p.y * tanh_fast(q4.y + e4.y)
                + v4p.z * tanh_fast(q4.z + e4.z) + v4p.w * tanh_fast(q4.w + e4.w);
        s = wave_sum(s);
        if (lane == 0) u_lds[r][n] = s;
      }
    }
    __syncthreads();
    // ---- F2: logits, log_softmax (clamped, no -inf!), argmax ----
    {
      const int r = wav, b = b0 + r;
      const bool mk = (lane < NSTEP) ? (mask_lds[r][lane] != 0) : true;
      const float lg = mk ? NEG_INF : (10.f * tanh_fast(u_lds[r][lane]));
      const float m  = wave_max(lg);
      const float ex = (lane < NSTEP) ? __expf(lg - m) : 0.f;
      const float ss = wave_sum(ex);
      const float ls = __logf(ss);
      if (lane < NSTEP)
        out[(size_t)b * (NSTEP * NSTEP) + (size_t)t * NSTEP + lane] =
            mk ? -1.0e30f : ((lg - m) - ls);
      float av = lg;
      int   ai = lane;
#pragma unroll
      for (int o = 1; o < 64; o <<= 1) {
        const float ov = __shfl_xor(av, o);
        const int   oi = __shfl_xor(ai, o);
        if (ov > av || (ov == av && oi < ai)) { av = ov; ai = oi; }
      }
      if (lane == 0) {
        idx_lds[r] = ai;
        out[OFF_SEL + (size_t)b * NSTEP + t] = (float)ai;
      }
    }
    __syncthreads();
    // ---- G: gathers + eta ----
    {
      float pr[RPB];
#pragma unroll
      for (int i = 0; i < RPB; ++i) {
        const int b  = b0 + i;
        const int ix = idx_lds[i];
        const float cur = context[((size_t)ix * BSZ + b) * HD + col];
        pr[i] = ln_reg[i] * lw0 + cur * lw1;
        ln_reg[i] = cur;
        nsel[i] = ix;
        if (!PRE) a_lds[i][col] = embedded[((size_t)ix * BSZ + b) * HD + col];
      }
#pragma unroll
      for (int o = 1; o < 64; o <<= 1) {
#pragma unroll
        for (int i = 0; i < RPB; ++i) pr[i] += __shfl_xor(pr[i], o);
      }
      if (lane == 0) {
#pragma unroll
        for (int i = 0; i < RPB; ++i) red_lds[wav][i] = pr[i];
      }
    }
    __syncthreads();
    if (tid < RPB) {
      const int r = tid;
      const float s = red_lds[0][r] + red_lds[1][r] + red_lds[2][r] + red_lds[3][r];
      const float ev = eta_lds[r] + s + etaB;
      eta_lds[r] = ev;
      out[OFF_ETA + (size_t)(b0 + r) * NSTEP + t] = ev;
      const int ix = idx_lds[r];
      mask_lds[r][ix] = 1;
      bool all = true;
      for (int n = 0; n < NSTEP; ++n) all = all && (mask_lds[r][n] != 0);
      if (all) mask_lds[r][NSTEP - 1] = 0;
    }
    __syncthreads();
  }
}

extern "C" void kernel_launch(void* const* d_in, const int* in_sizes, int n_in,
                              void* d_out, int out_size, void* d_ws, size_t ws_size,
                              hipStream_t stream) {
  const float* start_fea  = (const float*)d_in[0];
  const float* decoder_in = (const float*)d_in[1];
  const float* embedded   = (const float*)d_in[2];
  const float* hidden_h   = (const float*)d_in[3];
  const float* hidden_c   = (const float*)d_in[4];
  const float* context    = (const float*)d_in[5];
  // d_in[6] = V: unused by outputs
  const unsigned char* vmask = (const unsigned char*)d_in[7];
  const float* lstm_w_ih  = (const float*)d_in[8];
  const float* lstm_w_hh  = (const float*)d_in[9];
  const float* lstm_b_ih  = (const float*)d_in[10];
  const float* lstm_b_hh  = (const float*)d_in[11];
  const float* ptr_wq     = (const float*)d_in[12];
  const float* ptr_bq     = (const float*)d_in[13];
  const float* ptr_wr     = (const float*)d_in[14];
  const float* ptr_br     = (const float*)d_in[15];
  const float* ptr_v      = (const float*)d_in[16];
  const float* glp_wq     = (const float*)d_in[17];
  const float* glp_bq     = (const float*)d_in[18];
  const float* glp_wr     = (const float*)d_in[19];
  const float* glp_br     = (const float*)d_in[20];
  const float* glp_v      = (const float*)d_in[21];
  const float* fn_w       = (const float*)d_in[22];
  // d_in[23..26] = eta LSTM: dead code (outputs never read heh/cec)
  const float* eta_lw     = (const float*)d_in[27];
  const float* eta_lb     = (const float*)d_in[28];

  float* ws    = (float*)d_ws;
  float* e_glp = ws;                                       // 13,107,200 f32
  float* e_ptr = e_glp + (size_t)BSZ * NSTEP * HD;         // 13,107,200 f32
  float* wT2   = e_ptr + (size_t)BSZ * NSTEP * HD;         // 524,288 f32
  float* bc    = wT2 + (size_t)512 * 1024;                 // 1,024 f32
  float* zx    = bc + 1024;                                // 53,477,376 f32 (optional)

  const size_t need_pre =
      ((size_t)BSZ * NSTEP * HD * 2 + (size_t)512 * 1024 + 1024 +
       (size_t)(NSTEP + 1) * BSZ * 1024) * sizeof(float);
  const bool pre = (ws_size >= need_pre);

  init_kernel<<<516, 256, 0, stream>>>(lstm_w_ih, lstm_w_hh, lstm_b_ih, lstm_b_hh, wT2, bc);
  e_kernel<<<NSTEP * 32, 256, 0, stream>>>(context, glp_wr, glp_br, ptr_wr, ptr_br, e_glp, e_ptr);
  if (pre) {
    zx_kernel<<<(NSTEP + 1) * 32, 256, 0, stream>>>(embedded, decoder_in, wT2, zx);
    dec_kernel<1><<<BSZ / RPB, DEC_THREADS, 0, stream>>>(
        start_fea, decoder_in, embedded, hidden_h, hidden_c, context, vmask,
        glp_wq, glp_bq, glp_v, ptr_wq, ptr_bq, ptr_v,
        fn_w, eta_lw, eta_lb, wT2, bc, e_glp, e_ptr, zx, (float*)d_out);
  } else {
    dec_kernel<0><<<BSZ / RPB, DEC_THREADS, 0, stream>>>(
        start_fea, decoder_in, embedded, hidden_h, hidden_c, context, vmask,
        glp_wq, glp_bq, glp_v, ptr_wq, ptr_bq, ptr_v,
        fn_w, eta_lw, eta_lb, wT2, bc, e_glp, e_ptr, zx, (float*)d_out);
  }
}

// Round 4
// 5281.161 us; speedup vs baseline: 1.5268x; 1.5268x over previous
//
#include <hip/hip_runtime.h>
#include <hip/hip_bf16.h>

#define NSTEP 50
#define BSZ   1024
#define HD    256
#define RPB   4
#define NEG_INF (-__builtin_inff())

#define OFF_SEL ((size_t)BSZ * NSTEP * NSTEP)          // 2,560,000
#define OFF_ETA (OFF_SEL + (size_t)BSZ * NSTEP)        // 2,611,200

__device__ __forceinline__ float sigf(float x)      { return 1.f / (1.f + __expf(-x)); }
__device__ __forceinline__ float tanh_fast(float x) { return 1.f - 2.f / (__expf(2.f * x) + 1.f); }

__device__ __forceinline__ float wave_sum(float v) {
#pragma unroll
  for (int o = 1; o < 64; o <<= 1) v += __shfl_xor(v, o);
  return v;
}
__device__ __forceinline__ float wave_max(float v) {
#pragma unroll
  for (int o = 1; o < 64; o <<= 1) v = fmaxf(v, __shfl_xor(v, o));
  return v;
}

// wT2[k][4*col+g] = W[g*256+col][k]; bc[j]=b_ih[j]+b_hh[j]; wqT*[k][col] = wq[col][k]
__global__ __launch_bounds__(256) void init_kernel(
    const float* __restrict__ w_ih, const float* __restrict__ w_hh,
    const float* __restrict__ b_ih, const float* __restrict__ b_hh,
    const float* __restrict__ glp_wq, const float* __restrict__ ptr_wq,
    float* __restrict__ wT2, float* __restrict__ bc,
    float* __restrict__ wqTg, float* __restrict__ wqTp)
{
  const int bid = blockIdx.x, tid = threadIdx.x;
  if (bid < 512) {
    const int k = bid;
    const float* src = (k < 256) ? (w_ih + k) : (w_hh + (k - 256));
#pragma unroll
    for (int g = 0; g < 4; ++g)
      wT2[(size_t)k * 1024 + tid * 4 + g] = src[(size_t)(g * 256 + tid) * 256];
  } else if (bid < 516) {
    const int j = (bid - 512) * 256 + tid;
    bc[j] = b_ih[j] + b_hh[j];
  } else {
    const int k = bid - 516;
    wqTg[(size_t)k * 256 + tid] = glp_wq[(size_t)tid * 256 + k];
    wqTp[(size_t)k * 256 + tid] = ptr_wq[(size_t)tid * 256 + k];
  }
}

// e[b][n][g] = sum_h context[n][b][h]*wr[g][h] + br[g]
__global__ __launch_bounds__(256) void e_kernel(
    const float* __restrict__ context,
    const float* __restrict__ glp_wr, const float* __restrict__ glp_br,
    const float* __restrict__ ptr_wr, const float* __restrict__ ptr_br,
    float* __restrict__ e_glp, float* __restrict__ e_ptr)
{
  __shared__ float ctx_lds[32][256];
  const int tid = threadIdx.x;
  const int n   = blockIdx.x >> 5;
  const int b0  = (blockIdx.x & 31) << 5;
  const float* src = context + ((size_t)n * BSZ + b0) * HD;
  for (int i = tid; i < 32 * 64; i += 256) {
    const int row = i >> 6, k4 = (i & 63) << 2;
    *(float4*)&ctx_lds[row][k4] = *(const float4*)&src[row * HD + k4];
  }
  __syncthreads();
  const int g  = tid;
  const float bg = glp_br[g], bp = ptr_br[g];
  for (int rg = 0; rg < 2; ++rg) {
    float ag[16], ap[16];
#pragma unroll
    for (int i = 0; i < 16; ++i) { ag[i] = 0.f; ap[i] = 0.f; }
    for (int k = 0; k < 256; k += 4) {
      float4 wg = *(const float4*)&glp_wr[g * HD + k];
      float4 wp = *(const float4*)&ptr_wr[g * HD + k];
#pragma unroll
      for (int i = 0; i < 16; ++i) {
        float4 a = *(const float4*)&ctx_lds[rg * 16 + i][k];
        ag[i] += a.x * wg.x + a.y * wg.y + a.z * wg.z + a.w * wg.w;
        ap[i] += a.x * wp.x + a.y * wp.y + a.z * wp.z + a.w * wp.w;
      }
    }
#pragma unroll
    for (int i = 0; i < 16; ++i) {
      const int b = b0 + rg * 16 + i;
      e_glp[((size_t)b * NSTEP + n) * HD + g] = ag[i] + bg;
      e_ptr[((size_t)b * NSTEP + n) * HD + g] = ap[i] + bp;
    }
  }
}

// zx[n][b][4*col+g] = x_n[b] @ w_ih^T  (slot n==NSTEP -> decoder_input)
__global__ __launch_bounds__(256) void zx_kernel(
    const float* __restrict__ embedded, const float* __restrict__ decoder_input,
    const float* __restrict__ wT2, float* __restrict__ zx)
{
  __shared__ float x_lds[32][256];
  const int tid = threadIdx.x;
  const int n   = blockIdx.x >> 5;
  const int b0  = (blockIdx.x & 31) << 5;
  const float* src = (n < NSTEP) ? (embedded + ((size_t)n * BSZ + b0) * HD)
                                 : (decoder_input + (size_t)b0 * HD);
  for (int i = tid; i < 32 * 64; i += 256) {
    const int row = i >> 6, k4 = (i & 63) << 2;
    *(float4*)&x_lds[row][k4] = *(const float4*)&src[row * HD + k4];
  }
  __syncthreads();
  const float* wp = wT2 + (tid << 2);
  for (int rg = 0; rg < 2; ++rg) {
    float4 acc[16];
#pragma unroll
    for (int i = 0; i < 16; ++i) acc[i] = make_float4(0.f, 0.f, 0.f, 0.f);
    for (int k = 0; k < 256; k += 4) {
      float4 w0 = *(const float4*)(wp + (size_t)(k + 0) * 1024);
      float4 w1 = *(const float4*)(wp + (size_t)(k + 1) * 1024);
      float4 w2 = *(const float4*)(wp + (size_t)(k + 2) * 1024);
      float4 w3 = *(const float4*)(wp + (size_t)(k + 3) * 1024);
#pragma unroll
      for (int i = 0; i < 16; ++i) {
        float4 a = *(const float4*)&x_lds[rg * 16 + i][k];
        acc[i].x += a.x * w0.x + a.y * w1.x + a.z * w2.x + a.w * w3.x;
        acc[i].y += a.x * w0.y + a.y * w1.y + a.z * w2.y + a.w * w3.y;
        acc[i].z += a.x * w0.z + a.y * w1.z + a.z * w2.z + a.w * w3.z;
        acc[i].w += a.x * w0.w + a.y * w1.w + a.z * w2.w + a.w * w3.w;
      }
    }
#pragma unroll
    for (int i = 0; i < 16; ++i)
      *(float4*)&zx[((size_t)n * BSZ + (b0 + rg * 16 + i)) * 1024 + (tid << 2)] = acc[i];
  }
}

// persistent decoder: 256 blocks x 512 threads (8 waves), 4 rows/block, 50 steps
template <int PRE>
__global__ __launch_bounds__(512) void dec_kernel(
    const float* __restrict__ start_fea,
    const float* __restrict__ decoder_input,
    const float* __restrict__ embedded,
    const float* __restrict__ hidden_h,
    const float* __restrict__ hidden_c,
    const float* __restrict__ context,
    const unsigned char* __restrict__ vmask,
    const float* __restrict__ glp_bq, const float* __restrict__ glp_v,
    const float* __restrict__ ptr_bq, const float* __restrict__ ptr_v,
    const float* __restrict__ fn_w,
    const float* __restrict__ eta_lw, const float* __restrict__ eta_lb,
    const float* __restrict__ wT2, const float* __restrict__ bc,
    const float* __restrict__ wqTg, const float* __restrict__ wqTp,
    const float* __restrict__ e_glp, const float* __restrict__ e_ptr,
    const float* __restrict__ zx,
    float* __restrict__ out)
{
  __shared__ float a_lds[RPB][512];          // [r][0..255]=x (non-PRE), [r][256..511]=h
  __shared__ float z_lds[RPB][1024];         // A: z (4col+g); B/E: q parts [0,512); C: G parts [512,1024)
  __shared__ float u_lds[RPB][52];
  __shared__ unsigned char mask_lds[RPB][64];
  __shared__ float ms_lds[RPB][2][2];
  __shared__ int   idx_lds[RPB];
  __shared__ float red_lds[8][2];
  __shared__ float eta_lds[RPB];

  const int tid  = threadIdx.x;
  const int col  = tid & 255;
  const int hf   = tid >> 8;                 // 0/1 -> rows hf*2, hf*2+1
  const int wav  = tid >> 6;                 // 0..7
  const int lane = tid & 63;
  const int b0   = blockIdx.x * RPB;
  const int r2   = hf * 2;
  const int cwr  = wav >> 1;                 // C/F: row per wave-pair
  const int cwh  = wav & 1;                  // C/F: n-half
  const int n0   = cwh * 25;
  const int k0   = hf << 7;                  // B/E k-split

  float c_reg[2], ln_reg[2];

  // ---- init state ----
#pragma unroll
  for (int i2 = 0; i2 < 2; ++i2) {
    const int r = r2 + i2, b = b0 + r;
    a_lds[r][256 + col] = hidden_h[(size_t)b * HD + col];
    if (!PRE) a_lds[r][col] = decoder_input[(size_t)b * HD + col];
    c_reg[i2] = hidden_c[(size_t)b * HD + col];
    float fn = 0.f;
#pragma unroll
    for (int k = 0; k < 5; ++k) fn += start_fea[b * 5 + k] * fn_w[col * 5 + k];
    ln_reg[i2] = fn;
  }
  if (tid < RPB * NSTEP) {
    const int r = tid / NSTEP, n = tid - r * NSTEP;
    mask_lds[r][n] = vmask[(size_t)(b0 + r) * NSTEP + n];
  }
  if (tid < RPB) { eta_lds[tid] = 0.f; idx_lds[tid] = NSTEP; }
  __syncthreads();
  if (tid < RPB) {
    bool all = true;
    for (int n = 0; n < NSTEP; ++n) all = all && (mask_lds[tid][n] != 0);
    if (all) mask_lds[tid][NSTEP - 1] = 0;
  }
  __syncthreads();

  const float bch0 = bc[col], bch1 = bc[col + 256], bch2 = bc[col + 512], bch3 = bc[col + 768];
  const float lw0 = eta_lw[col], lw1 = eta_lw[HD + col];
  const float etaB = eta_lb[0];
  const float4 v4g  = *(const float4*)&glp_v[lane << 2];
  const float4 v4p  = *(const float4*)&ptr_v[lane << 2];
  const float4 v4bg = *(const float4*)&glp_bq[lane << 2];
  const float4 v4bp = *(const float4*)&ptr_bq[lane << 2];
  const int j2 = tid * 2;

  for (int t = 0; t < NSTEP; ++t) {
    // ---- A: z[j2,j2+1] for all 4 rows; W read once per block ----
    {
      float2 acc[RPB];
      if (PRE) {
#pragma unroll
        for (int i = 0; i < RPB; ++i)
          acc[i] = *(const float2*)&zx[((size_t)idx_lds[i] * BSZ + (b0 + i)) * 1024 + j2];
      } else {
#pragma unroll
        for (int i = 0; i < RPB; ++i) acc[i] = make_float2(0.f, 0.f);
      }
      const int K0 = PRE ? 256 : 0;
      for (int k = K0; k < 512; k += 4) {
        float4 a4[RPB];
#pragma unroll
        for (int i = 0; i < RPB; ++i) a4[i] = *(const float4*)&a_lds[i][k];
        float2 w0 = *(const float2*)&wT2[(size_t)(k + 0) * 1024 + j2];
        float2 w1 = *(const float2*)&wT2[(size_t)(k + 1) * 1024 + j2];
        float2 w2 = *(const float2*)&wT2[(size_t)(k + 2) * 1024 + j2];
        float2 w3 = *(const float2*)&wT2[(size_t)(k + 3) * 1024 + j2];
#pragma unroll
        for (int i = 0; i < RPB; ++i) {
          acc[i].x += a4[i].x * w0.x + a4[i].y * w1.x + a4[i].z * w2.x + a4[i].w * w3.x;
          acc[i].y += a4[i].x * w0.y + a4[i].y * w1.y + a4[i].z * w2.y + a4[i].w * w3.y;
        }
      }
#pragma unroll
      for (int i = 0; i < RPB; ++i) *(float2*)&z_lds[i][j2] = acc[i];
    }
    __syncthreads();
    // ---- gates (read z_lds [4col+g]); write h ----
#pragma unroll
    for (int i2 = 0; i2 < 2; ++i2) {
      const int r = r2 + i2;
      const float4 z4 = *(const float4*)&z_lds[r][col << 2];
      const float zi = z4.x + bch0, zf = z4.y + bch1, zg = z4.z + bch2, zo = z4.w + bch3;
      const float cn = sigf(zf) * c_reg[i2] + sigf(zi) * tanh_fast(zg);
      c_reg[i2] = cn;
      a_lds[r][256 + col] = sigf(zo) * tanh_fast(cn);
    }
    __syncthreads();
    // ---- B: q_glp partials, k-split over hf; wq read once per block ----
    {
      float accB[RPB] = {0.f, 0.f, 0.f, 0.f};
      for (int k = k0; k < k0 + 128; k += 4) {
        float4 a4[RPB];
#pragma unroll
        for (int i = 0; i < RPB; ++i) a4[i] = *(const float4*)&a_lds[i][256 + k];
        const float w0 = wqTg[(size_t)(k + 0) * 256 + col];
        const float w1 = wqTg[(size_t)(k + 1) * 256 + col];
        const float w2 = wqTg[(size_t)(k + 2) * 256 + col];
        const float w3 = wqTg[(size_t)(k + 3) * 256 + col];
#pragma unroll
        for (int i = 0; i < RPB; ++i)
          accB[i] += a4[i].x * w0 + a4[i].y * w1 + a4[i].z * w2 + a4[i].w * w3;
      }
#pragma unroll
      for (int i = 0; i < RPB; ++i) z_lds[i][(hf << 8) + col] = accB[i];
    }
    __syncthreads();
    // ---- C: fused glimpse (online softmax + weighted sum; e_glp read ONCE) ----
    {
      const int r = cwr, b = b0 + r;
      float4 q4;
      {
        const float4 p0 = *(const float4*)&z_lds[r][lane << 2];
        const float4 p1 = *(const float4*)&z_lds[r][256 + (lane << 2)];
        q4 = make_float4(p0.x + p1.x + v4bg.x, p0.y + p1.y + v4bg.y,
                         p0.z + p1.z + v4bg.z, p0.w + p1.w + v4bg.w);
      }
      float m = NEG_INF, s = 0.f;
      float4 G = make_float4(0.f, 0.f, 0.f, 0.f);
      const float* eb = e_glp + (size_t)b * NSTEP * HD;
      for (int n = n0; n < n0 + 25; ++n) {
        if (mask_lds[r][n]) continue;
        const float4 e4 = *(const float4*)&eb[n * HD + (lane << 2)];
        float uu = v4g.x * tanh_fast(q4.x + e4.x) + v4g.y * tanh_fast(q4.y + e4.y)
                 + v4g.z * tanh_fast(q4.z + e4.z) + v4g.w * tanh_fast(q4.w + e4.w);
        uu = wave_sum(uu);
        if (uu > m) {
          const float sc = __expf(m - uu);
          s *= sc; G.x *= sc; G.y *= sc; G.z *= sc; G.w *= sc;
          m = uu;
        }
        const float p = __expf(uu - m);
        s += p;
        G.x += p * e4.x; G.y += p * e4.y; G.z += p * e4.z; G.w += p * e4.w;
      }
      if (lane == 0) { ms_lds[r][cwh][0] = m; ms_lds[r][cwh][1] = s; }
      __syncthreads();
      const float mo = ms_lds[r][cwh ^ 1][0], so = ms_lds[r][cwh ^ 1][1];
      const float mg = fmaxf(m, mo);
      const float Z  = s * __expf(m - mg) + so * __expf(mo - mg);
      const float sc = __expf(m - mg) / Z;
      G.x *= sc; G.y *= sc; G.z *= sc; G.w *= sc;
      *(float4*)&z_lds[r][512 + (cwh << 8) + (lane << 2)] = G;
    }
    __syncthreads();
    // ---- E: q_ptr partials from g_l = G0+G1, k-split over hf ----
    {
      float accE[RPB] = {0.f, 0.f, 0.f, 0.f};
      for (int k = k0; k < k0 + 128; k += 4) {
        float4 g4[RPB];
#pragma unroll
        for (int i = 0; i < RPB; ++i) {
          const float4 ga = *(const float4*)&z_lds[i][512 + k];
          const float4 gb = *(const float4*)&z_lds[i][768 + k];
          g4[i] = make_float4(ga.x + gb.x, ga.y + gb.y, ga.z + gb.z, ga.w + gb.w);
        }
        const float w0 = wqTp[(size_t)(k + 0) * 256 + col];
        const float w1 = wqTp[(size_t)(k + 1) * 256 + col];
        const float w2 = wqTp[(size_t)(k + 2) * 256 + col];
        const float w3 = wqTp[(size_t)(k + 3) * 256 + col];
#pragma unroll
        for (int i = 0; i < RPB; ++i)
          accE[i] += g4[i].x * w0 + g4[i].y * w1 + g4[i].z * w2 + g4[i].w * w3;
      }
#pragma unroll
      for (int i = 0; i < RPB; ++i) z_lds[i][(hf << 8) + col] = accE[i];
    }
    __syncthreads();
    // ---- F: u_ptr (2 waves per row, 25 n each) ----
    {
      const int r = cwr, b = b0 + r;
      float4 q4;
      {
        const float4 p0 = *(const float4*)&z_lds[r][lane << 2];
        const float4 p1 = *(const float4*)&z_lds[r][256 + (lane << 2)];
        q4 = make_float4(p0.x + p1.x + v4bp.x, p0.y + p1.y + v4bp.y,
                         p0.z + p1.z + v4bp.z, p0.w + p1.w + v4bp.w);
      }
      const float* eb = e_ptr + (size_t)b * NSTEP * HD;
      for (int n = n0; n < n0 + 25; ++n) {
        const float4 e4 = *(const float4*)&eb[n * HD + (lane << 2)];
        float uu = v4p.x * tanh_fast(q4.x + e4.x) + v4p.y * tanh_fast(q4.y + e4.y)
                 + v4p.z * tanh_fast(q4.z + e4.z) + v4p.w * tanh_fast(q4.w + e4.w);
        uu = wave_sum(uu);
        if (lane == 0) u_lds[r][n] = uu;
      }
    }
    __syncthreads();
    // ---- F2: logits, log_softmax (finite clamp), argmax (waves 0..3) ----
    if (wav < RPB) {
      const int r = wav, b = b0 + r;
      const bool mk = (lane < NSTEP) ? (mask_lds[r][lane] != 0) : true;
      const float lg = mk ? NEG_INF : (10.f * tanh_fast(u_lds[r][lane]));
      const float m  = wave_max(lg);
      const float ex = (lane < NSTEP) ? __expf(lg - m) : 0.f;
      const float ss = wave_sum(ex);
      const float ls = __logf(ss);
      if (lane < NSTEP)
        out[(size_t)b * (NSTEP * NSTEP) + (size_t)t * NSTEP + lane] =
            mk ? -1.0e30f : ((lg - m) - ls);
      float av = lg;
      int   ai = lane;
#pragma unroll
      for (int o = 1; o < 64; o <<= 1) {
        const float ov = __shfl_xor(av, o);
        const int   oi = __shfl_xor(ai, o);
        if (ov > av || (ov == av && oi < ai)) { av = ov; ai = oi; }
      }
      if (lane == 0) {
        idx_lds[r] = ai;
        out[OFF_SEL + (size_t)b * NSTEP + t] = (float)ai;
      }
    }
    __syncthreads();
    // ---- G: gathers + eta ----
    {
      float pr[2];
#pragma unroll
      for (int i2 = 0; i2 < 2; ++i2) {
        const int r = r2 + i2, b = b0 + r;
        const int ix = idx_lds[r];
        const float cur = context[((size_t)ix * BSZ + b) * HD + col];
        pr[i2] = ln_reg[i2] * lw0 + cur * lw1;
        ln_reg[i2] = cur;
        if (!PRE) a_lds[r][col] = embedded[((size_t)ix * BSZ + b) * HD + col];
      }
#pragma unroll
      for (int o = 1; o < 64; o <<= 1) {
        pr[0] += __shfl_xor(pr[0], o);
        pr[1] += __shfl_xor(pr[1], o);
      }
      if (lane == 0) { red_lds[wav][0] = pr[0]; red_lds[wav][1] = pr[1]; }
    }
    __syncthreads();
    if (tid < RPB) {
      const int r = tid, hfr = r >> 1, i2 = r & 1;
      const float s = red_lds[hfr * 4 + 0][i2] + red_lds[hfr * 4 + 1][i2]
                    + red_lds[hfr * 4 + 2][i2] + red_lds[hfr * 4 + 3][i2];
      const float ev = eta_lds[r] + s + etaB;
      eta_lds[r] = ev;
      out[OFF_ETA + (size_t)(b0 + r) * NSTEP + t] = ev;
      const int ix = idx_lds[r];
      mask_lds[r][ix] = 1;
      bool all = true;
      for (int n = 0; n < NSTEP; ++n) all = all && (mask_lds[r][n] != 0);
      if (all) mask_lds[r][NSTEP - 1] = 0;
    }
    __syncthreads();
  }
}

extern "C" void kernel_launch(void* const* d_in, const int* in_sizes, int n_in,
                              void* d_out, int out_size, void* d_ws, size_t ws_size,
                              hipStream_t stream) {
  const float* start_fea  = (const float*)d_in[0];
  const float* decoder_in = (const float*)d_in[1];
  const float* embedded   = (const float*)d_in[2];
  const float* hidden_h   = (const float*)d_in[3];
  const float* hidden_c   = (const float*)d_in[4];
  const float* context    = (const float*)d_in[5];
  // d_in[6] = V: unused by outputs
  const unsigned char* vmask = (const unsigned char*)d_in[7];
  const float* lstm_w_ih  = (const float*)d_in[8];
  const float* lstm_w_hh  = (const float*)d_in[9];
  const float* lstm_b_ih  = (const float*)d_in[10];
  const float* lstm_b_hh  = (const float*)d_in[11];
  const float* ptr_wq     = (const float*)d_in[12];
  const float* ptr_bq     = (const float*)d_in[13];
  const float* ptr_wr     = (const float*)d_in[14];
  const float* ptr_br     = (const float*)d_in[15];
  const float* ptr_v      = (const float*)d_in[16];
  const float* glp_wq     = (const float*)d_in[17];
  const float* glp_bq     = (const float*)d_in[18];
  const float* glp_wr     = (const float*)d_in[19];
  const float* glp_br     = (const float*)d_in[20];
  const float* glp_v      = (const float*)d_in[21];
  const float* fn_w       = (const float*)d_in[22];
  // d_in[23..26] = eta LSTM: dead code (outputs never read heh/cec)
  const float* eta_lw     = (const float*)d_in[27];
  const float* eta_lb     = (const float*)d_in[28];

  float* ws    = (float*)d_ws;
  float* e_glp = ws;                                       // 13,107,200 f32
  float* e_ptr = e_glp + (size_t)BSZ * NSTEP * HD;         // 13,107,200 f32
  float* wT2   = e_ptr + (size_t)BSZ * NSTEP * HD;         // 524,288 f32
  float* bc    = wT2 + (size_t)512 * 1024;                 // 1,024 f32
  float* wqTg  = bc + 1024;                                // 65,536 f32
  float* wqTp  = wqTg + 65536;                             // 65,536 f32
  float* zx    = wqTp + 65536;                             // 53,477,376 f32 (optional)

  const size_t need_pre =
      ((size_t)BSZ * NSTEP * HD * 2 + (size_t)512 * 1024 + 1024 + 2 * 65536 +
       (size_t)(NSTEP + 1) * BSZ * 1024) * sizeof(float);
  const bool pre = (ws_size >= need_pre);

  init_kernel<<<772, 256, 0, stream>>>(lstm_w_ih, lstm_w_hh, lstm_b_ih, lstm_b_hh,
                                       glp_wq, ptr_wq, wT2, bc, wqTg, wqTp);
  e_kernel<<<NSTEP * 32, 256, 0, stream>>>(context, glp_wr, glp_br, ptr_wr, ptr_br, e_glp, e_ptr);
  if (pre) {
    zx_kernel<<<(NSTEP + 1) * 32, 256, 0, stream>>>(embedded, decoder_in, wT2, zx);
    dec_kernel<1><<<BSZ / RPB, 512, 0, stream>>>(
        start_fea, decoder_in, embedded, hidden_h, hidden_c, context, vmask,
        glp_bq, glp_v, ptr_bq, ptr_v, fn_w, eta_lw, eta_lb,
        wT2, bc, wqTg, wqTp, e_glp, e_ptr, zx, (float*)d_out);
  } else {
    dec_kernel<0><<<BSZ / RPB, 512, 0, stream>>>(
        start_fea, decoder_in, embedded, hidden_h, hidden_c, context, vmask,
        glp_bq, glp_v, ptr_bq, ptr_v, fn_w, eta_lw, eta_lb,
        wT2, bc, wqTg, wqTp, e_glp, e_ptr, zx, (float*)d_out);
  }
}